// Round 3
// baseline (660.202 us; speedup 1.0000x reference)
//
#include <hip/hip_runtime.h>

// Problem constants (from reference setup)
constexpr int N_ = 2, Z_ = 40, Y_ = 400, X_ = 400;
constexpr int G_ = 30000;     // grid query positions
constexpr int M_ = 120000;    // feature rows
constexpr int C_ = 64;        // channels
constexpr int K_ = 64;        // neighborhood size (p=4 -> 4^3)

constexpr int GPB   = 8;           // g per block -> 2KB-contiguous writes per plane
constexpr int SLOTS = GPB * K_;    // 512 (g,k) slots per block
constexpr int CG    = 16;          // channels per LDS group
constexpr int NGRP  = C_ / CG;     // 4 groups
// LDS row stride: 516 dwords. 516*4B is 16B-aligned (ds_read_b128 ok) and
// 516 mod 32 = 4 -> transpose-writes are <=2-way bank aliased (free, m136).
constexpr int STR   = SLOTS + 4;   // 516

// Output layout (flat, in return order):
//   sampled_features: [C, G, K]  = C*G*K floats
//   gpf:              [4, G, K]
//   empty_mask:       [G]

__global__ __launch_bounds__(512) void grouper_kernel(
    const int*   __restrict__ voxel_maps,     // [N,Z,Y,X]
    const int*   __restrict__ grid_positions, // [G,4]
    const float* __restrict__ features,       // [M,C]
    const int*   __restrict__ index_offset,   // [1,K,4]
    float*       __restrict__ out)
{
    __shared__ float s_feat[CG * STR];   // 33.0 KB, transposed [c][slot]
    __shared__ int   s_idx[SLOTS];       // 2 KB

    // Bijective XCD-aware swizzle (m204): each XCD owns a contiguous g-range
    // so its L2 accumulates contiguous dirty spans -> streaming writebacks.
    constexpr int NWG = G_ / GPB;        // 3750
    constexpr int NX  = 8;
    constexpr int q_  = NWG / NX;        // 468
    constexpr int r_  = NWG % NX;        // 6
    const int bid = blockIdx.x;
    const int xcd = bid % NX, bi = bid / NX;
    const int swz = (xcd < r_) ? xcd * (q_ + 1) + bi
                               : r_ * (q_ + 1) + (xcd - r_) * q_ + bi;
    const int g0 = swz * GPB;

    const int t    = threadIdx.x;        // 512 threads
    const int lane = t & 63;
    const int w    = t >> 6;             // wave id == local g index

    const long long GK = (long long)G_ * K_;
    float* out_sf   = out;                              // [C,G,K]
    float* out_gpf  = out + (long long)C_ * GK;         // [4,G,K]
    float* out_mask = out + (long long)(C_ + 4) * GK;   // [G]

    // ---------------- phase 0: voxel lookup, mask, gpf ----------------
    const int4 off = ((const int4*)index_offset)[lane];       // per-lane, coalesced
    const int4 gp  = ((const int4*)grid_positions)[g0 + w];   // wave-uniform

    const int n = gp.x + off.x;                               // off.x == 0 (no clip)
    const int z = min(max(gp.y + off.y, 0), Z_ - 1);
    const int y = min(max(gp.z + off.z, 0), Y_ - 1);
    const int x = min(max(gp.w + off.w, 0), X_ - 1);

    const int sidx = voxel_maps[((n * Z_ + z) * Y_ + y) * X_ + x];
    s_idx[t] = sidx;

    // empty mask: all sidx == -1 across this wave's 64 k
    const bool all_empty = __all(sidx == -1);
    if (lane == 0) out_mask[g0 + w] = all_empty ? 1.0f : 0.0f;

    // gpf: integer positions contribute 0 after (x - floor(x)); only offsets
    // remain. Dense 2 KB run per plane per block.
    const long long base_gk = (long long)g0 * K_;
    out_gpf[0 * GK + base_gk + t] = (float)off.x;
    out_gpf[1 * GK + base_gk + t] = (float)off.y;
    out_gpf[2 * GK + base_gk + t] = (float)off.z;
    out_gpf[3 * GK + base_gk + t] = (float)off.w;

    __syncthreads();   // publish s_idx

    // ---------------- channel-group pipeline ----------------
    const int rq = t >> 2;   // row-slot base within sweep (0..127)
    const int qc = t & 3;    // float4 column within group (4 consecutive channels)

    for (int grp = 0; grp < NGRP; ++grp) {
        // Gather: 4 sweeps x 128 rows; 4 threads/row read a dense 64 B piece
        // -> per wave-instr 16 dense 64 B segments. Issued BEFORE the barrier
        // so the loads overlap the previous group's stores.
        float4 v[4];
        #pragma unroll
        for (int s = 0; s < 4; ++s) {
            const int slot = s * 128 + rq;
            const int si   = s_idx[slot];
            float4 vv = make_float4(0.f, 0.f, 0.f, 0.f);
            if (si >= 0)
                vv = ((const float4*)(features + (long long)si * C_))[grp * 4 + qc];
            v[s] = vv;
        }

        if (grp) __syncthreads();   // previous group's LDS reads done

        // Transpose into LDS: channel (qc*4+i), slot. <=2-way bank alias.
        #pragma unroll
        for (int s = 0; s < 4; ++s) {
            const int slot = s * 128 + rq;
            s_feat[(qc * 4 + 0) * STR + slot] = v[s].x;
            s_feat[(qc * 4 + 1) * STR + slot] = v[s].y;
            s_feat[(qc * 4 + 2) * STR + slot] = v[s].z;
            s_feat[(qc * 4 + 3) * STR + slot] = v[s].w;
        }
        __syncthreads();

        // Store: wave w owns local channels {2w, 2w+1}; each (c) plane gets a
        // dense 2 KB run (two 1 KB wave-instructions, consecutive).
        #pragma unroll
        for (int cc = 0; cc < 2; ++cc) {
            const int cl = w * 2 + cc;            // local channel 0..15
            const int c  = grp * CG + cl;         // global channel
            #pragma unroll
            for (int h = 0; h < 2; ++h) {
                const int sq = h * 64 + lane;     // float4 quad 0..127
                const float4 vv = *(const float4*)&s_feat[cl * STR + sq * 4];
                *(float4*)(out_sf + (long long)c * GK + base_gk + sq * 4) = vv;
            }
        }
    }
}

extern "C" void kernel_launch(void* const* d_in, const int* in_sizes, int n_in,
                              void* d_out, int out_size, void* d_ws, size_t ws_size,
                              hipStream_t stream) {
    const int*   voxel_maps     = (const int*)d_in[0];
    const int*   grid_positions = (const int*)d_in[1];
    const float* features       = (const float*)d_in[2];
    const int*   index_offset   = (const int*)d_in[3];
    float*       out            = (float*)d_out;

    grouper_kernel<<<G_ / GPB, 512, 0, stream>>>(
        voxel_maps, grid_positions, features, index_offset, out);
}